// Round 13
// baseline (439.507 us; speedup 1.0000x reference)
//
#include <hip/hip_runtime.h>
#include <hip/hip_bf16.h>

// DGCF forward, MI355X. f32 in/out.
// R13: revert R12's fusion (traffic-invariant, regressed). R11 structure +
// ILP: k_scores_edge 2 edges/thread (split halves, head-broadcast preserved),
// k_dinv2 unroll-2.
#define NUSER 50000
#define NITEM 50000
#define NN    100000          // NUSER+NITEM
#define NNZ_  1000000
#define DIM_  64
#define NBLK  391             // ceil_div(NN,256) == bucket count
#define EPB   2560            // edges per bin-pass block (391*2560 >= NNZ)
#define HALF  (NNZ_ / 2)

#define FL_SVC    1   // svals == 0.25 (iteration 0)
#define FL_FN     2   // store fn (bf16) for the scores pass
#define FL_OUT    4   // out += fn
#define FL_NEXT   8   // write ego_next / te_next
#define FL_FIN    16  // out = (out + fn) / 3
#define FL_ACONST 32  // scores: A_old == 1
#define FL_ASTORE 64  // scores: store A_new

static inline int ceil_div(int a, int b) { return (a + b - 1) / b; }

static __device__ inline float bf2f(unsigned short u) {
    return __uint_as_float(((unsigned int)u) << 16);
}
static __device__ inline float blo(unsigned int u) {
    return __uint_as_float(u << 16);
}
static __device__ inline float bhi(unsigned int u) {
    return __uint_as_float(u & 0xffff0000u);
}
static __device__ inline unsigned short f2bf(float f) {
    unsigned int x = __float_as_uint(f);
    x += 0x7fffu + ((x >> 16) & 1u);
    return (unsigned short)(x >> 16);
}

// ego = concat(user,item) bf16; te = tanh(l2norm chunk16) bf16; out = ego f32.
__global__ void k_init(const float* __restrict__ eu, const float* __restrict__ ei,
                       unsigned short* __restrict__ ego, unsigned short* __restrict__ te,
                       float* __restrict__ out) {
    int i = blockIdx.x * 256 + threadIdx.x;
    if (i >= NN * DIM_) return;
    float v = (i < NUSER * DIM_) ? eu[i] : ei[i - NUSER * DIM_];
    out[i] = v;
    ego[i] = f2bf(v);
    float s = v * v;
    s += __shfl_xor(s, 1); s += __shfl_xor(s, 2);
    s += __shfl_xor(s, 4); s += __shfl_xor(s, 8);
    float nrm = v / fmaxf(sqrtf(s), 1e-12f);
    float ex = __expf(2.0f * nrm);
    te[i] = f2bf((ex - 1.0f) / (ex + 1.0f));
}

// ---- bucketed CSR build (once per launch) ----
__global__ void k_bcount(const int* __restrict__ head, int* __restrict__ bcount) {
    __shared__ int cnt[NBLK];
    int tid = threadIdx.x;
    for (int i = tid; i < NBLK; i += 256) cnt[i] = 0;
    __syncthreads();
    int e0 = blockIdx.x * EPB;
    int e1 = min(e0 + EPB, NNZ_);
    for (int e = e0 + tid; e < e1; e += 256)
        atomicAdd(&cnt[head[e] >> 8], 1);
    __syncthreads();
    for (int i = tid; i < NBLK; i += 256)
        if (cnt[i]) atomicAdd(&bcount[i], cnt[i]);
}

__global__ void k_bscan(const int* __restrict__ bcount, int* __restrict__ bucket_base,
                        int* __restrict__ bucket_cursor, int* __restrict__ row_start_end) {
    __shared__ int sh[512];
    int t = threadIdx.x;
    int v = (t < NBLK) ? bcount[t] : 0;
    sh[t] = v;
    __syncthreads();
    for (int off = 1; off < 512; off <<= 1) {
        int u = 0;
        if (t >= off) u = sh[t - off];
        __syncthreads();
        sh[t] += u;
        __syncthreads();
    }
    if (t < NBLK) {
        int base = sh[t] - v;
        bucket_base[t] = base;
        bucket_cursor[t] = base;
    }
    if (t == 511) {
        bucket_base[NBLK] = sh[511];    // == NNZ_
        row_start_end[0] = sh[511];
    }
}

__global__ void k_binscat(const int* __restrict__ head, const int* __restrict__ tail,
                          int* __restrict__ bucket_cursor, int2* __restrict__ bin) {
    __shared__ int cnt[NBLK];
    __shared__ int chunk[NBLK];
    int tid = threadIdx.x;
    for (int i = tid; i < NBLK; i += 256) cnt[i] = 0;
    __syncthreads();
    int e0 = blockIdx.x * EPB;
    int e1 = min(e0 + EPB, NNZ_);
    for (int e = e0 + tid; e < e1; e += 256)
        atomicAdd(&cnt[head[e] >> 8], 1);
    __syncthreads();
    for (int i = tid; i < NBLK; i += 256) {
        chunk[i] = cnt[i] ? atomicAdd(&bucket_cursor[i], cnt[i]) : 0;
        cnt[i] = 0;   // reuse as local cursor
    }
    __syncthreads();
    for (int e = e0 + tid; e < e1; e += 256) {
        int h = head[e], t = tail[e];
        int b = h >> 8;
        int off = atomicAdd(&cnt[b], 1);
        bin[chunk[b] + off] = make_int2(h, t);
    }
}

__global__ void k_bucket(const int2* __restrict__ bin, const int* __restrict__ bucket_base,
                         int* __restrict__ row_start, float4* __restrict__ d4a,
                         int* __restrict__ csr_tail) {
    __shared__ int deg[256];
    __shared__ int sh[256];
    __shared__ int cur[256];
    int tid = threadIdx.x;
    int b = blockIdx.x;
    int n0 = b << 8;
    int e0 = bucket_base[b], e1 = bucket_base[b + 1];
    deg[tid] = 0;
    __syncthreads();
    for (int e = e0 + tid; e < e1; e += 256)
        atomicAdd(&deg[bin[e].x - n0], 1);
    __syncthreads();
    int myDeg = deg[tid];
    sh[tid] = myDeg;
    __syncthreads();
    for (int off = 1; off < 256; off <<= 1) {
        int u = 0;
        if (tid >= off) u = sh[tid - off];
        __syncthreads();
        sh[tid] += u;
        __syncthreads();
    }
    int loff = sh[tid] - myDeg;
    int n = n0 + tid;
    if (n < NN) {
        row_start[n] = e0 + loff;
        float dd = (myDeg > 0) ? 2.0f / sqrtf((float)myDeg) : 0.0f;
        d4a[n] = make_float4(dd, dd, dd, dd);
    }
    cur[tid] = e0 + loff;
    __syncthreads();
    for (int e = e0 + tid; e < e1; e += 256) {
        int2 p = bin[e];
        int pos = atomicAdd(&cur[p.x - n0], 1);
        csr_tail[pos] = p.y;
    }
}

// csr_head is piecewise-constant in CSR order: fill node-parallel, coalesced.
__global__ void k_headfill(const int* __restrict__ row_start, int* __restrict__ csr_head) {
    int n = blockIdx.x * 256 + threadIdx.x;
    if (n >= NN) return;
    int r0 = row_start[n], r1 = row_start[n + 1];
    for (int k = r0; k < r1; ++k) csr_head[k] = n;
}

// ---- walk1: one wave per node, 4 edges per step ----
// lane = 16*q + l: q = edge slot (0..3), l = dim quad (dims 4l..4l+3), f = l>>2.
template<int FLAGS>
__global__ void k_iter(const unsigned short* __restrict__ svals,  // bf16 [NNZ*4]
                       const float* __restrict__ d4c,             // f32 [NN*4]
                       const unsigned short* __restrict__ ego,    // bf16 [NN*64]
                       const int* __restrict__ row_start, const int* __restrict__ csr_tail,
                       float* __restrict__ out,
                       unsigned short* __restrict__ fnb,          // bf16 [NN*64]
                       unsigned short* __restrict__ egon, unsigned short* __restrict__ ten) {
    int n = (blockIdx.x * 256 + threadIdx.x) >> 6;
    if (n >= NN) return;
    int lane = threadIdx.x & 63;
    int q = lane >> 4;
    int l = lane & 15;
    int f = l >> 2;
    int r0 = __builtin_amdgcn_readfirstlane(row_start[n]);
    int r1 = __builtin_amdgcn_readfirstlane(row_start[n + 1]);

    float ax = 0.f, ay = 0.f, az = 0.f, aw = 0.f;
    int kb = r0;
    for (; kb + 7 < r1; kb += 8) {
        int i0 = kb + q, i1 = kb + 4 + q;
        int t0 = csr_tail[i0], t1 = csr_tail[i1];
        float w0, w1;
        if (FLAGS & FL_SVC) { w0 = 0.25f; w1 = 0.25f; }
        else { w0 = bf2f(svals[i0 * 4 + f]); w1 = bf2f(svals[i1 * 4 + f]); }
        w0 *= d4c[t0 * 4 + f]; w1 *= d4c[t1 * 4 + f];
        ushort4 u0 = *(const ushort4*)(ego + (size_t)t0 * 64 + 4 * l);
        ushort4 u1 = *(const ushort4*)(ego + (size_t)t1 * 64 + 4 * l);
        ax += w0 * bf2f(u0.x) + w1 * bf2f(u1.x);
        ay += w0 * bf2f(u0.y) + w1 * bf2f(u1.y);
        az += w0 * bf2f(u0.z) + w1 * bf2f(u1.z);
        aw += w0 * bf2f(u0.w) + w1 * bf2f(u1.w);
    }
    for (; kb < r1; kb += 4) {
        int i0 = kb + q;
        bool v = (i0 < r1);
        int ic = v ? i0 : r0;
        int t0 = csr_tail[ic];
        float w0 = (FLAGS & FL_SVC) ? 0.25f : bf2f(svals[ic * 4 + f]);
        w0 *= d4c[t0 * 4 + f];
        w0 = v ? w0 : 0.0f;
        ushort4 u0 = *(const ushort4*)(ego + (size_t)t0 * 64 + 4 * l);
        ax += w0 * bf2f(u0.x); ay += w0 * bf2f(u0.y);
        az += w0 * bf2f(u0.z); aw += w0 * bf2f(u0.w);
    }

    ax += __shfl_xor(ax, 16); ax += __shfl_xor(ax, 32);
    ay += __shfl_xor(ay, 16); ay += __shfl_xor(ay, 32);
    az += __shfl_xor(az, 16); az += __shfl_xor(az, 32);
    aw += __shfl_xor(aw, 16); aw += __shfl_xor(aw, 32);
    float s = ax * ax + ay * ay + az * az + aw * aw;
    s += __shfl_xor(s, 1); s += __shfl_xor(s, 2);
    float inv = 1.0f / fmaxf(sqrtf(s), 1e-12f);
    float fx = ax * inv, fy = ay * inv, fz = az * inv, fw = aw * inv;

    if (q == 0) {
        if (FLAGS & FL_FN) {
            ushort4 o; o.x = f2bf(fx); o.y = f2bf(fy); o.z = f2bf(fz); o.w = f2bf(fw);
            *(ushort4*)(fnb + (size_t)n * 64 + 4 * l) = o;
        }
        if (FLAGS & FL_FIN) {
            float4* po = (float4*)(out + (size_t)n * 64 + 4 * l);
            float4 ov = *po;
            ov.x = (ov.x + fx) * (1.0f / 3.0f); ov.y = (ov.y + fy) * (1.0f / 3.0f);
            ov.z = (ov.z + fz) * (1.0f / 3.0f); ov.w = (ov.w + fw) * (1.0f / 3.0f);
            *po = ov;
        } else if (FLAGS & FL_OUT) {
            float4* po = (float4*)(out + (size_t)n * 64 + 4 * l);
            float4 ov = *po;
            ov.x += fx; ov.y += fy; ov.z += fz; ov.w += fw;
            *po = ov;
        }
        if (FLAGS & FL_NEXT) {
            ushort4 o; o.x = f2bf(fx); o.y = f2bf(fy); o.z = f2bf(fz); o.w = f2bf(fw);
            *(ushort4*)(egon + (size_t)n * 64 + 4 * l) = o;
            float e0 = __expf(2.0f * fx), e1 = __expf(2.0f * fy);
            float e2 = __expf(2.0f * fz), e3 = __expf(2.0f * fw);
            ushort4 p;
            p.x = f2bf((e0 - 1.0f) / (e0 + 1.0f)); p.y = f2bf((e1 - 1.0f) / (e1 + 1.0f));
            p.z = f2bf((e2 - 1.0f) / (e2 + 1.0f)); p.w = f2bf((e3 - 1.0f) / (e3 + 1.0f));
            *(ushort4*)(ten + (size_t)n * 64 + 4 * l) = p;
        }
    }
}

// ---- scores + A-update + softmax, edge-parallel, 2 edges/thread ----
// Thread handles edge e (lower half) and e+HALF (upper half): two independent
// gather chains in flight; consecutive threads keep head-sharing broadcast.
template<int FLAGS>
__device__ inline void score_one(int e, float4* __restrict__ A4,
                                 const unsigned short* __restrict__ fnb,
                                 const unsigned short* __restrict__ te,
                                 const int* __restrict__ csr_head,
                                 const int* __restrict__ csr_tail,
                                 ushort4* __restrict__ svals) {
    int h = csr_head[e], t = csr_tail[e];
    const uint4* fh = (const uint4*)(fnb + (size_t)h * 64);
    const uint4* tv = (const uint4*)(te + (size_t)t * 64);
    float4 a = (FLAGS & FL_ACONST) ? make_float4(1.f, 1.f, 1.f, 1.f) : A4[e];
    float p[4];
#pragma unroll
    for (int f = 0; f < 4; ++f) {
        uint4 u0 = fh[f * 2], u1 = fh[f * 2 + 1];
        uint4 v0 = tv[f * 2], v1 = tv[f * 2 + 1];
        float s = blo(u0.x) * blo(v0.x) + bhi(u0.x) * bhi(v0.x)
                + blo(u0.y) * blo(v0.y) + bhi(u0.y) * bhi(v0.y)
                + blo(u0.z) * blo(v0.z) + bhi(u0.z) * bhi(v0.z)
                + blo(u0.w) * blo(v0.w) + bhi(u0.w) * bhi(v0.w)
                + blo(u1.x) * blo(v1.x) + bhi(u1.x) * bhi(v1.x)
                + blo(u1.y) * blo(v1.y) + bhi(u1.y) * bhi(v1.y)
                + blo(u1.z) * blo(v1.z) + bhi(u1.z) * bhi(v1.z)
                + blo(u1.w) * blo(v1.w) + bhi(u1.w) * bhi(v1.w);
        p[f] = s;
    }
    a.x += p[0]; a.y += p[1]; a.z += p[2]; a.w += p[3];
    if (FLAGS & FL_ASTORE) A4[e] = a;
    float e0 = __expf(a.x), e1 = __expf(a.y), e2 = __expf(a.z), e3 = __expf(a.w);
    float inv = 1.0f / (e0 + e1 + e2 + e3);
    ushort4 o;
    o.x = f2bf(e0 * inv); o.y = f2bf(e1 * inv);
    o.z = f2bf(e2 * inv); o.w = f2bf(e3 * inv);
    svals[e] = o;
}

template<int FLAGS>
__global__ void k_scores_edge(float4* __restrict__ A4,
                              const unsigned short* __restrict__ fnb,
                              const unsigned short* __restrict__ te,
                              const int* __restrict__ csr_head,
                              const int* __restrict__ csr_tail,
                              ushort4* __restrict__ svals) {
    int e = blockIdx.x * 256 + threadIdx.x;
    if (e >= HALF) return;
    score_one<FLAGS>(e, A4, fnb, te, csr_head, csr_tail, svals);
    score_one<FLAGS>(e + HALF, A4, fnb, te, csr_head, csr_tail, svals);
}

// rowsum of svals per node -> d4n (thread/node), unroll-2.
__global__ void k_dinv2(const ushort4* __restrict__ svals, const int* __restrict__ row_start,
                        float4* __restrict__ d4n) {
    int n = blockIdx.x * 256 + threadIdx.x;
    if (n >= NN) return;
    int r0 = row_start[n], r1 = row_start[n + 1];
    float s0 = 0.f, s1 = 0.f, s2 = 0.f, s3 = 0.f;
    float t0 = 0.f, t1 = 0.f, t2 = 0.f, t3 = 0.f;
    int k = r0;
    for (; k + 1 < r1; k += 2) {
        ushort4 v = svals[k];
        ushort4 w = svals[k + 1];
        s0 += bf2f(v.x); s1 += bf2f(v.y); s2 += bf2f(v.z); s3 += bf2f(v.w);
        t0 += bf2f(w.x); t1 += bf2f(w.y); t2 += bf2f(w.z); t3 += bf2f(w.w);
    }
    if (k < r1) {
        ushort4 v = svals[k];
        s0 += bf2f(v.x); s1 += bf2f(v.y); s2 += bf2f(v.z); s3 += bf2f(v.w);
    }
    s0 += t0; s1 += t1; s2 += t2; s3 += t3;
    float4 d;
    d.x = (s0 > 0.f) ? 1.0f / sqrtf(fmaxf(s0, 1e-12f)) : 0.f;
    d.y = (s1 > 0.f) ? 1.0f / sqrtf(fmaxf(s1, 1e-12f)) : 0.f;
    d.z = (s2 > 0.f) ? 1.0f / sqrtf(fmaxf(s2, 1e-12f)) : 0.f;
    d.w = (s3 > 0.f) ? 1.0f / sqrtf(fmaxf(s3, 1e-12f)) : 0.f;
    d4n[n] = d;
}

extern "C" void kernel_launch(void* const* d_in, const int* in_sizes, int n_in,
                              void* d_out, int out_size, void* d_ws, size_t ws_size,
                              hipStream_t stream) {
    const float* eu = (const float*)d_in[0];
    const float* ei = (const float*)d_in[1];
    const int* head = (const int*)d_in[2];
    const int* tail = (const int*)d_in[3];
    float* out = (float*)d_out;   // 3-term accumulator, scaled at it3 (FL_FIN)

    // workspace layout — ~108 MB (16B-aligned first)
    float* A4 = (float*)d_ws;                               // 16 MB
    float* d4a = A4 + (size_t)NNZ_ * 4;                     // 1.6 MB
    float* d4b = d4a + (size_t)NN * 4;                      // 1.6 MB
    unsigned short* svals = (unsigned short*)(d4b + (size_t)NN * 4);  // 8 MB
    unsigned short* ego_a = svals + (size_t)NNZ_ * 4;       // 12.8 MB
    unsigned short* te_a  = ego_a + (size_t)NN * DIM_;      // 12.8 MB
    unsigned short* ego_b = te_a + (size_t)NN * DIM_;       // 12.8 MB
    unsigned short* te_b  = ego_b + (size_t)NN * DIM_;      // 12.8 MB
    unsigned short* fnb   = te_b + (size_t)NN * DIM_;       // 12.8 MB
    int2* bin = (int2*)(fnb + (size_t)NN * DIM_);           // 8 MB
    int* csr_tail = (int*)(bin + NNZ_);                     // 4 MB
    int* csr_head = csr_tail + NNZ_;                        // 4 MB
    int* row_start = csr_head + NNZ_;                       // NN+1
    int* bcount = row_start + (NN + 1);                     // NBLK
    int* bucket_base = bcount + NBLK;                       // NBLK+1
    int* bucket_cursor = bucket_base + (NBLK + 1);          // NBLK

    const int node_blocks = ceil_div(NN * DIM_, 256);      // 25000
    const int half_blocks = ceil_div(HALF, 256);           // 1954
    const int wave_blocks = ceil_div(NN * 64, 256);        // 25000
    const int dinv_blocks = ceil_div(NN, 256);             // 391

    k_init<<<node_blocks, 256, 0, stream>>>(eu, ei, ego_a, te_a, out);

    // bucketed CSR build + d4_0 seed
    hipMemsetAsync(bcount, 0, NBLK * sizeof(int), stream);
    k_bcount<<<NBLK, 256, 0, stream>>>(head, bcount);
    k_bscan<<<1, 512, 0, stream>>>(bcount, bucket_base, bucket_cursor, &row_start[NN]);
    k_binscat<<<NBLK, 256, 0, stream>>>(head, tail, bucket_cursor, bin);
    k_bucket<<<NBLK, 256, 0, stream>>>(bin, bucket_base, row_start, (float4*)d4a, csr_tail);
    k_headfill<<<dinv_blocks, 256, 0, stream>>>(row_start, csr_head);

    // it0 = (0,0): walk1 with svals==0.25; fn -> fnb; scores A_old==1, store A_1.
    k_iter<FL_SVC | FL_FN><<<wave_blocks, 256, 0, stream>>>(
        svals, d4a, ego_a, row_start, csr_tail, out, fnb, ego_b, te_b);
    k_scores_edge<FL_ACONST | FL_ASTORE><<<half_blocks, 256, 0, stream>>>(
        (float4*)A4, fnb, te_a, csr_head, csr_tail, (ushort4*)svals);
    k_dinv2<<<dinv_blocks, 256, 0, stream>>>((const ushort4*)svals, row_start, (float4*)d4b);

    // it1 = (0,1): layer-0 output; fn doubles as next ego (scores reads ego_b).
    k_iter<FL_OUT | FL_NEXT><<<wave_blocks, 256, 0, stream>>>(
        svals, d4b, ego_a, row_start, csr_tail, out, fnb, ego_b, te_b);
    k_scores_edge<FL_ASTORE><<<half_blocks, 256, 0, stream>>>(
        (float4*)A4, ego_b, te_a, csr_head, csr_tail, (ushort4*)svals);
    k_dinv2<<<dinv_blocks, 256, 0, stream>>>((const ushort4*)svals, row_start, (float4*)d4a);

    // it2 = (1,0): fn -> fnb; scores store of A_3 dead (never read again).
    k_iter<FL_FN><<<wave_blocks, 256, 0, stream>>>(
        svals, d4a, ego_b, row_start, csr_tail, out, fnb, ego_a, te_a);
    k_scores_edge<0><<<half_blocks, 256, 0, stream>>>(
        (float4*)A4, fnb, te_b, csr_head, csr_tail, (ushort4*)svals);
    k_dinv2<<<dinv_blocks, 256, 0, stream>>>((const ushort4*)svals, row_start, (float4*)d4b);

    // it3 = (1,1): no scores (dead); final out = (out + fn) / 3.
    k_iter<FL_OUT | FL_FIN><<<wave_blocks, 256, 0, stream>>>(
        svals, d4b, ego_b, row_start, csr_tail, out, fnb, ego_a, te_a);
}